// Round 1
// baseline (36574.405 us; speedup 1.0000x reference)
//
#include <hip/hip_runtime.h>
#include <math.h>
#include <cstddef>

// Problem constants
#define BATCH 4
#define HDIM 256      // attention H  (== conv channel dim)
#define WDIM 256      // attention W  (== conv H)
#define CDIM 128      // attention C  (== conv W)
#define WS 4
#define SHIFT 3
#define HEADS 4
#define HD 32
#define NTOK 16       // WS*WS

__device__ __forceinline__ int regionOf(int v) {
    // slices: [0,252) -> 0, [252,253) -> 1, [253,256) -> 2
    return v < (WDIM - WS) ? 0 : (v < (WDIM - SHIFT) ? 1 : 2);
}

// ---------------------------------------------------------------------------
// Kernel A: fused bilinear-2x upsample (align_corners) + shifted-window MSA
//           + residual.  One block per window. 256 threads.
// Input  xin : (4, 256, 128, 64)  raw
// Output xatt: (4, 256, 256, 128) = upsampled + attention output
// ---------------------------------------------------------------------------
__global__ __launch_bounds__(256) void attn_kernel(
    const float* __restrict__ xin,
    const float* __restrict__ qkv_w,    // (128, 384)
    const float* __restrict__ qkv_b,    // (384)
    const float* __restrict__ proj_w,   // (128, 128)
    const float* __restrict__ proj_b,   // (128)
    const float* __restrict__ rpb,      // (49, 4)
    float* __restrict__ xatt)
{
    __shared__ float xrow[NTOK][2][64];   // two raw rows per token
    __shared__ float xw_t[CDIM][NTOK];    // upsampled token features, [c][n]
    __shared__ float qkv[NTOK][3 * CDIM]; // (n, 384)
    __shared__ float attnS[HEADS][NTOK][NTOK];
    __shared__ float otok_t[CDIM][NTOK];  // attn output, [c][n]
    __shared__ float tokw2[NTOK];

    const int tid = threadIdx.x;
    const int bid = blockIdx.x;
    const int b  = bid >> 12;          // 4096 windows per batch
    const int wh = (bid >> 6) & 63;
    const int ww = bid & 63;

    // ---- Stage 1: load the two raw input rows each token needs -----------
    {
        int n = tid >> 4;      // token 0..15
        int l = tid & 15;      // lane within token
        int r = n >> 2, c = n & 3;
        int gh = (wh * 4 + r + SHIFT) & 255;   // roll(-s) read == rolled-back write pos
        int gw = (ww * 4 + c + SHIFT) & 255;
        float pos2 = gw * (127.0f / 255.0f);
        int lo2 = (int)floorf(pos2);
        int hi2 = min(lo2 + 1, 127);
        float w2 = pos2 - (float)lo2;
        if (l == 0) tokw2[n] = w2;
        const float4* r0 = (const float4*)(xin + (((size_t)b * 256 + gh) * 128 + lo2) * 64);
        const float4* r1 = (const float4*)(xin + (((size_t)b * 256 + gh) * 128 + hi2) * 64);
        ((float4*)&xrow[n][0][0])[l] = r0[l];
        ((float4*)&xrow[n][1][0])[l] = r1[l];
    }
    __syncthreads();

    // ---- Stage 2: bilinear interp along last axis -> xw_t[c][n] ----------
    {
        int n = tid >> 4;
        int l = tid & 15;
        float w2 = tokw2[n];
        #pragma unroll
        for (int i = 0; i < 8; i++) {
            int cc = l * 8 + i;
            float pos3 = cc * (63.0f / 127.0f);
            int lo3 = (int)floorf(pos3);
            int hi3 = min(lo3 + 1, 63);
            float w3 = pos3 - (float)lo3;
            float v0 = xrow[n][0][lo3] * (1.f - w3) + xrow[n][0][hi3] * w3;
            float v1 = xrow[n][1][lo3] * (1.f - w3) + xrow[n][1][hi3] * w3;
            xw_t[cc][n] = v0 * (1.f - w2) + v1 * w2;
        }
    }
    __syncthreads();

    // ---- Stage 3: QKV = xw @ qkv_w + qkv_b  (column-major threading) -----
    {
        #pragma unroll
        for (int pass = 0; pass < 2; pass++) {
            int j = pass * 256 + tid;
            if (j < 384) {
                float acc[NTOK];
                #pragma unroll
                for (int n = 0; n < NTOK; n++) acc[n] = 0.f;
                for (int cc = 0; cc < CDIM; cc++) {
                    float wv = qkv_w[cc * 384 + j];
                    #pragma unroll
                    for (int n = 0; n < NTOK; n++) acc[n] += xw_t[cc][n] * wv;
                }
                float bj = qkv_b[j];
                #pragma unroll
                for (int n = 0; n < NTOK; n++) qkv[n][j] = acc[n] + bj;
            }
        }
    }
    __syncthreads();

    // ---- Stage 4: attention scores + bias + mask -------------------------
    {
        #pragma unroll
        for (int i = 0; i < 4; i++) {
            int idx = tid * 4 + i;          // 0..1023 = (h, n, m)
            int h = idx >> 8;
            int n = (idx >> 4) & 15;
            int m = idx & 15;
            const float* qp = &qkv[n][h * HD];
            const float* kp = &qkv[m][CDIM + h * HD];
            float acc = 0.f;
            #pragma unroll
            for (int d = 0; d < HD; d++) acc += qp[d] * kp[d];
            acc *= 0.17677669529663687f;    // 32^-0.5
            int r1 = n >> 2, c1 = n & 3, r2 = m >> 2, c2 = m & 3;
            int ridx = (r1 - r2 + 3) * 7 + (c1 - c2 + 3);
            acc += rpb[ridx * 4 + h];
            int reg1 = regionOf(wh * 4 + r1) * 3 + regionOf(ww * 4 + c1);
            int reg2 = regionOf(wh * 4 + r2) * 3 + regionOf(ww * 4 + c2);
            if (reg1 != reg2) acc -= 100.f;
            attnS[h][n][m] = acc;
        }
    }
    __syncthreads();

    // ---- Stage 5: softmax over keys (64 rows) ----------------------------
    if (tid < 64) {
        int h = tid >> 4, n = tid & 15;
        float mx = -1e30f;
        #pragma unroll
        for (int m = 0; m < NTOK; m++) mx = fmaxf(mx, attnS[h][n][m]);
        float e[NTOK];
        float s = 0.f;
        #pragma unroll
        for (int m = 0; m < NTOK; m++) { e[m] = expf(attnS[h][n][m] - mx); s += e[m]; }
        float inv = 1.f / s;
        #pragma unroll
        for (int m = 0; m < NTOK; m++) attnS[h][n][m] = e[m] * inv;
    }
    __syncthreads();

    // ---- Stage 6: P @ V -> otok_t[c][n] ----------------------------------
    {
        int n = tid >> 4;
        int l = tid & 15;
        #pragma unroll
        for (int i = 0; i < 8; i++) {
            int cc = l * 8 + i;
            int h = cc >> 5;
            const float* pp = &attnS[h][n][0];
            float acc = 0.f;
            #pragma unroll
            for (int m = 0; m < NTOK; m++) acc += pp[m] * qkv[m][2 * CDIM + cc];
            otok_t[cc][n] = acc;
        }
    }
    __syncthreads();

    // ---- Stage 7: proj + bias + shortcut, store (rolled-back position) ---
    {
        int j  = tid & 127;
        int nh = tid >> 7;   // 0/1 -> tokens [0,8) / [8,16)
        float acc[8];
        #pragma unroll
        for (int i = 0; i < 8; i++) acc[i] = 0.f;
        for (int cc = 0; cc < CDIM; cc++) {
            float wv = proj_w[cc * CDIM + j];
            #pragma unroll
            for (int i = 0; i < 8; i++) acc[i] += otok_t[cc][nh * 8 + i] * wv;
        }
        float bj = proj_b[j];
        #pragma unroll
        for (int i = 0; i < 8; i++) {
            int n = nh * 8 + i;
            int r = n >> 2, c = n & 3;
            int gh = (wh * 4 + r + SHIFT) & 255;
            int gw = (ww * 4 + c + SHIFT) & 255;
            xatt[(((size_t)b * 256 + gh) * 256 + gw) * 128 + j] = acc[i] + bj + xw_t[j][n];
        }
    }
}

// ---------------------------------------------------------------------------
// Kernel B: direct 3x3 conv (pad 1) + BN (+ optional ReLU), NCHW view
//   N=4, C=256, H=256, W=128.  Block = (n, co, 2 rows x 128 cols).
// ---------------------------------------------------------------------------
__global__ __launch_bounds__(256) void conv3x3_bn(
    const float* __restrict__ xin,
    const float* __restrict__ wgt,   // (256,256,3,3)
    const float* __restrict__ bias,  // (256)
    const float* __restrict__ bng, const float* __restrict__ bnb,
    const float* __restrict__ bnm, const float* __restrict__ bnv,
    float* __restrict__ out, int do_relu)
{
    __shared__ float wts[2304];        // this co's 256x3x3 weights
    __shared__ float tile[4][520];     // 4 ci x (4 rows x 130 cols)

    const int tid = threadIdx.x;
    const int bid = blockIdx.x;
    const int co = bid & 255;                 // innermost: L2 tile reuse
    const int h0 = ((bid >> 8) & 127) * 2;
    const int n  = bid >> 15;

    for (int i = tid; i < 2304; i += 256) wts[i] = wgt[(size_t)co * 2304 + i];

    const int r = tid >> 7;     // 0..1
    const int w = tid & 127;
    float acc = 0.f;

    for (int cb = 0; cb < 256; cb += 4) {
        __syncthreads();
        for (int i = tid; i < 2080; i += 256) {
            int q   = i / 520;
            int rem = i - q * 520;
            int row = rem / 130;
            int col = rem - row * 130 - 1;
            int hh  = h0 - 1 + row;
            float v = 0.f;
            if ((unsigned)hh < 256u && (unsigned)col < 128u)
                v = xin[(((size_t)n * 256 + (cb + q)) * 256 + hh) * 128 + col];
            tile[q][rem] = v;
        }
        __syncthreads();
        #pragma unroll
        for (int q = 0; q < 4; q++) {
            const float* wp = &wts[(cb + q) * 9];
            const float* tp = &tile[q][0];
            #pragma unroll
            for (int kh = 0; kh < 3; kh++) {
                #pragma unroll
                for (int kw = 0; kw < 3; kw++) {
                    acc += tp[(r + kh) * 130 + w + kw] * wp[kh * 3 + kw];
                }
            }
        }
    }
    float s  = bng[co] * rsqrtf(bnv[co] + 1e-5f);
    float sh = bnb[co] - bnm[co] * s;
    float y  = (acc + bias[co]) * s + sh;
    if (do_relu) y = fmaxf(y, 0.f);
    out[(((size_t)n * 256 + co) * 256 + (h0 + r)) * 128 + w] = y;
}

// ---------------------------------------------------------------------------
// Kernel C: conv2(3x3)+BN2  +  identity conv1x1+BNi  ->  ReLU(sum)
// ---------------------------------------------------------------------------
__global__ __launch_bounds__(256) void conv_final(
    const float* __restrict__ y1,    // conv2 input
    const float* __restrict__ xatt,  // 1x1 identity input
    const float* __restrict__ w2, const float* __restrict__ b2,
    const float* __restrict__ g2, const float* __restrict__ bb2,
    const float* __restrict__ m2, const float* __restrict__ v2,
    const float* __restrict__ wi, const float* __restrict__ bi,
    const float* __restrict__ gi, const float* __restrict__ bbi,
    const float* __restrict__ mi, const float* __restrict__ vi,
    float* __restrict__ out)
{
    __shared__ float wts[2304];
    __shared__ float wid[256];
    __shared__ float tile[4][520];
    __shared__ float xtile[4][256];   // 4 ci x (2 rows x 128 cols), no halo

    const int tid = threadIdx.x;
    const int bid = blockIdx.x;
    const int co = bid & 255;
    const int h0 = ((bid >> 8) & 127) * 2;
    const int n  = bid >> 15;

    for (int i = tid; i < 2304; i += 256) wts[i] = w2[(size_t)co * 2304 + i];
    if (tid < 256) wid[tid] = wi[(size_t)co * 256 + tid];

    const int r = tid >> 7;
    const int w = tid & 127;
    float acc = 0.f;   // 3x3 path
    float acc2 = 0.f;  // 1x1 path

    for (int cb = 0; cb < 256; cb += 4) {
        __syncthreads();
        for (int i = tid; i < 2080; i += 256) {
            int q   = i / 520;
            int rem = i - q * 520;
            int row = rem / 130;
            int col = rem - row * 130 - 1;
            int hh  = h0 - 1 + row;
            float v = 0.f;
            if ((unsigned)hh < 256u && (unsigned)col < 128u)
                v = y1[(((size_t)n * 256 + (cb + q)) * 256 + hh) * 128 + col];
            tile[q][rem] = v;
        }
        for (int i = tid; i < 1024; i += 256) {
            int q   = i >> 8;
            int rem = i & 255;
            int row = rem >> 7;
            int col = rem & 127;
            xtile[q][rem] = xatt[(((size_t)n * 256 + (cb + q)) * 256 + (h0 + row)) * 128 + col];
        }
        __syncthreads();
        #pragma unroll
        for (int q = 0; q < 4; q++) {
            const float* wp = &wts[(cb + q) * 9];
            const float* tp = &tile[q][0];
            #pragma unroll
            for (int kh = 0; kh < 3; kh++) {
                #pragma unroll
                for (int kw = 0; kw < 3; kw++) {
                    acc += tp[(r + kh) * 130 + w + kw] * wp[kh * 3 + kw];
                }
            }
            acc2 += xtile[q][r * 128 + w] * wid[cb + q];
        }
    }
    float s2  = g2[co] * rsqrtf(v2[co] + 1e-5f);
    float sh2 = bb2[co] - m2[co] * s2;
    float si  = gi[co] * rsqrtf(vi[co] + 1e-5f);
    float shi = bbi[co] - mi[co] * si;
    float ya  = (acc  + b2[co]) * s2 + sh2;
    float yb  = (acc2 + bi[co]) * si + shi;
    out[(((size_t)n * 256 + co) * 256 + (h0 + r)) * 128 + w] = fmaxf(ya + yb, 0.f);
}

// ---------------------------------------------------------------------------
extern "C" void kernel_launch(void* const* d_in, const int* in_sizes, int n_in,
                              void* d_out, int out_size, void* d_ws, size_t ws_size,
                              hipStream_t stream) {
    const float* x       = (const float*)d_in[0];
    const float* qkv_w   = (const float*)d_in[1];
    const float* qkv_b   = (const float*)d_in[2];
    const float* proj_w  = (const float*)d_in[3];
    const float* proj_b  = (const float*)d_in[4];
    const float* rpb     = (const float*)d_in[5];
    const float* conv1_w = (const float*)d_in[6];
    const float* conv1_b = (const float*)d_in[7];
    const float* bn1_g   = (const float*)d_in[8];
    const float* bn1_b   = (const float*)d_in[9];
    const float* bn1_m   = (const float*)d_in[10];
    const float* bn1_v   = (const float*)d_in[11];
    const float* conv2_w = (const float*)d_in[12];
    const float* conv2_b = (const float*)d_in[13];
    const float* bn2_g   = (const float*)d_in[14];
    const float* bn2_b   = (const float*)d_in[15];
    const float* bn2_m   = (const float*)d_in[16];
    const float* bn2_v   = (const float*)d_in[17];
    const float* idc_w   = (const float*)d_in[18];
    const float* idc_b   = (const float*)d_in[19];
    const float* bni_g   = (const float*)d_in[20];
    const float* bni_b   = (const float*)d_in[21];
    const float* bni_m   = (const float*)d_in[22];
    const float* bni_v   = (const float*)d_in[23];

    const size_t TENSOR_ELEMS = (size_t)BATCH * 256 * 256 * 128;  // 33,554,432
    float* xatt = (float*)d_ws;
    float* y1   = (float*)((char*)d_ws + TENSOR_ELEMS * sizeof(float));
    float* out  = (float*)d_out;

    attn_kernel<<<16384, 256, 0, stream>>>(x, qkv_w, qkv_b, proj_w, proj_b, rpb, xatt);
    conv3x3_bn<<<131072, 256, 0, stream>>>(xatt, conv1_w, conv1_b,
                                           bn1_g, bn1_b, bn1_m, bn1_v, y1, 1);
    conv_final<<<131072, 256, 0, stream>>>(y1, xatt,
                                           conv2_w, conv2_b, bn2_g, bn2_b, bn2_m, bn2_v,
                                           idc_w, idc_b, bni_g, bni_b, bni_m, bni_v, out);
}

// Round 2
// 1673.356 us; speedup vs baseline: 21.8569x; 21.8569x over previous
//
#include <hip/hip_runtime.h>
#include <hip/hip_bf16.h>
#include <math.h>
#include <cstddef>

// Problem constants
#define BATCH 4
#define WDIM 256
#define CDIM 128
#define WS 4
#define SHIFT 3
#define HEADS 4
#define HD 32
#define NTOK 16

typedef __attribute__((ext_vector_type(8))) short short8;
typedef __attribute__((ext_vector_type(4))) int int4v;
typedef __attribute__((ext_vector_type(4))) float f32x4;

__device__ __forceinline__ int regionOf(int v) {
    return v < (WDIM - WS) ? 0 : (v < (WDIM - SHIFT) ? 1 : 2);
}

// ---------------------------------------------------------------------------
// Kernel A: fused bilinear-2x upsample (align_corners) + shifted-window MSA
//           + residual.  One block per window. 256 threads.  Output bf16.
// ---------------------------------------------------------------------------
__global__ __launch_bounds__(256) void attn_kernel(
    const float* __restrict__ xin,
    const float* __restrict__ qkv_w,    // (128, 384)
    const float* __restrict__ qkv_b,    // (384)
    const float* __restrict__ proj_w,   // (128, 128)
    const float* __restrict__ proj_b,   // (128)
    const float* __restrict__ rpb,      // (49, 4)
    __hip_bfloat16* __restrict__ xatt)
{
    __shared__ float xrow[NTOK][2][64];
    __shared__ float xw_t[CDIM][NTOK];
    __shared__ float qkv[NTOK][3 * CDIM];
    __shared__ float attnS[HEADS][NTOK][NTOK];
    __shared__ float otok_t[CDIM][NTOK];
    __shared__ float tokw2[NTOK];

    const int tid = threadIdx.x;
    const int bid = blockIdx.x;
    const int b  = bid >> 12;
    const int wh = (bid >> 6) & 63;
    const int ww = bid & 63;

    {
        int n = tid >> 4;
        int l = tid & 15;
        int r = n >> 2, c = n & 3;
        int gh = (wh * 4 + r + SHIFT) & 255;
        int gw = (ww * 4 + c + SHIFT) & 255;
        float pos2 = gw * (127.0f / 255.0f);
        int lo2 = (int)floorf(pos2);
        int hi2 = min(lo2 + 1, 127);
        float w2 = pos2 - (float)lo2;
        if (l == 0) tokw2[n] = w2;
        const float4* r0 = (const float4*)(xin + (((size_t)b * 256 + gh) * 128 + lo2) * 64);
        const float4* r1 = (const float4*)(xin + (((size_t)b * 256 + gh) * 128 + hi2) * 64);
        ((float4*)&xrow[n][0][0])[l] = r0[l];
        ((float4*)&xrow[n][1][0])[l] = r1[l];
    }
    __syncthreads();

    {
        int n = tid >> 4;
        int l = tid & 15;
        float w2 = tokw2[n];
        #pragma unroll
        for (int i = 0; i < 8; i++) {
            int cc = l * 8 + i;
            float pos3 = cc * (63.0f / 127.0f);
            int lo3 = (int)floorf(pos3);
            int hi3 = min(lo3 + 1, 63);
            float w3 = pos3 - (float)lo3;
            float v0 = xrow[n][0][lo3] * (1.f - w3) + xrow[n][0][hi3] * w3;
            float v1 = xrow[n][1][lo3] * (1.f - w3) + xrow[n][1][hi3] * w3;
            xw_t[cc][n] = v0 * (1.f - w2) + v1 * w2;
        }
    }
    __syncthreads();

    {
        #pragma unroll
        for (int pass = 0; pass < 2; pass++) {
            int j = pass * 256 + tid;
            if (j < 384) {
                float acc[NTOK];
                #pragma unroll
                for (int n = 0; n < NTOK; n++) acc[n] = 0.f;
                for (int cc = 0; cc < CDIM; cc++) {
                    float wv = qkv_w[cc * 384 + j];
                    #pragma unroll
                    for (int n = 0; n < NTOK; n++) acc[n] += xw_t[cc][n] * wv;
                }
                float bj = qkv_b[j];
                #pragma unroll
                for (int n = 0; n < NTOK; n++) qkv[n][j] = acc[n] + bj;
            }
        }
    }
    __syncthreads();

    {
        #pragma unroll
        for (int i = 0; i < 4; i++) {
            int idx = tid * 4 + i;
            int h = idx >> 8;
            int n = (idx >> 4) & 15;
            int m = idx & 15;
            const float* qp = &qkv[n][h * HD];
            const float* kp = &qkv[m][CDIM + h * HD];
            float acc = 0.f;
            #pragma unroll
            for (int d = 0; d < HD; d++) acc += qp[d] * kp[d];
            acc *= 0.17677669529663687f;
            int r1 = n >> 2, c1 = n & 3, r2 = m >> 2, c2 = m & 3;
            int ridx = (r1 - r2 + 3) * 7 + (c1 - c2 + 3);
            acc += rpb[ridx * 4 + h];
            int reg1 = regionOf(wh * 4 + r1) * 3 + regionOf(ww * 4 + c1);
            int reg2 = regionOf(wh * 4 + r2) * 3 + regionOf(ww * 4 + c2);
            if (reg1 != reg2) acc -= 100.f;
            attnS[h][n][m] = acc;
        }
    }
    __syncthreads();

    if (tid < 64) {
        int h = tid >> 4, n = tid & 15;
        float mx = -1e30f;
        #pragma unroll
        for (int m = 0; m < NTOK; m++) mx = fmaxf(mx, attnS[h][n][m]);
        float e[NTOK];
        float s = 0.f;
        #pragma unroll
        for (int m = 0; m < NTOK; m++) { e[m] = expf(attnS[h][n][m] - mx); s += e[m]; }
        float inv = 1.f / s;
        #pragma unroll
        for (int m = 0; m < NTOK; m++) attnS[h][n][m] = e[m] * inv;
    }
    __syncthreads();

    {
        int n = tid >> 4;
        int l = tid & 15;
        #pragma unroll
        for (int i = 0; i < 8; i++) {
            int cc = l * 8 + i;
            int h = cc >> 5;
            const float* pp = &attnS[h][n][0];
            float acc = 0.f;
            #pragma unroll
            for (int m = 0; m < NTOK; m++) acc += pp[m] * qkv[m][2 * CDIM + cc];
            otok_t[cc][n] = acc;
        }
    }
    __syncthreads();

    {
        int j  = tid & 127;
        int nh = tid >> 7;
        float acc[8];
        #pragma unroll
        for (int i = 0; i < 8; i++) acc[i] = 0.f;
        for (int cc = 0; cc < CDIM; cc++) {
            float wv = proj_w[cc * CDIM + j];
            #pragma unroll
            for (int i = 0; i < 8; i++) acc[i] += otok_t[cc][nh * 8 + i] * wv;
        }
        float bj = proj_b[j];
        #pragma unroll
        for (int i = 0; i < 8; i++) {
            int n = nh * 8 + i;
            int r = n >> 2, c = n & 3;
            int gh = (wh * 4 + r + SHIFT) & 255;
            int gw = (ww * 4 + c + SHIFT) & 255;
            xatt[(((size_t)b * 256 + gh) * 256 + gw) * 128 + j] =
                __float2bfloat16(acc[i] + bj + xw_t[j][n]);
        }
    }
}

// ---------------------------------------------------------------------------
// Weight repack: fold BN scale, fp32 -> bf16, per-tap MFMA-friendly layout.
// wrep[g][cb][tap][col(128)][ci(32)]  for the 3x3 convs
// ---------------------------------------------------------------------------
__global__ __launch_bounds__(256) void repack3(
    const float* __restrict__ w, const float* __restrict__ bias,
    const float* __restrict__ g_, const float* __restrict__ b_,
    const float* __restrict__ m_, const float* __restrict__ v_,
    __hip_bfloat16* __restrict__ wrep, float* __restrict__ cconst)
{
    int idx = blockIdx.x * 256 + threadIdx.x;       // < 589824
    int co = idx / 2304;
    int rem = idx - co * 2304;
    int ci = rem / 9;
    int tap = rem - ci * 9;
    float s = g_[co] * rsqrtf(v_[co] + 1e-5f);
    size_t o = ((((size_t)(co >> 7) * 8 + (ci >> 5)) * 9 + tap) * 128 + (co & 127)) * 32 + (ci & 31);
    wrep[o] = __float2bfloat16(w[idx] * s);
    if (rem == 0) cconst[co] = bias[co] * s + (b_[co] - m_[co] * s);
}

// wrepi[g][cb][col(128)][ci(32)] for the 1x1 identity conv; ADDS its constant
// into cconst (which repack3 for conv2 initialized earlier on the stream).
__global__ __launch_bounds__(256) void repack1(
    const float* __restrict__ w, const float* __restrict__ bias,
    const float* __restrict__ g_, const float* __restrict__ b_,
    const float* __restrict__ m_, const float* __restrict__ v_,
    __hip_bfloat16* __restrict__ wrep, float* __restrict__ cconst)
{
    int idx = blockIdx.x * 256 + threadIdx.x;       // < 65536
    int co = idx >> 8, ci = idx & 255;
    float s = g_[co] * rsqrtf(v_[co] + 1e-5f);
    wrep[(((size_t)(co >> 7) * 8 + (ci >> 5)) * 128 + (co & 127)) * 32 + (ci & 31)] =
        __float2bfloat16(w[idx] * s);
    if (ci == 0) cconst[co] += bias[co] * s + (b_[co] - m_[co] * s);
}

// ---------------------------------------------------------------------------
// MFMA implicit-GEMM 3x3 conv (+ optional fused 1x1 identity branch).
// Block: 128 co x 128 w (one output row h).  4 waves of 64x64, 4x4 frags.
// K-loop: 8 ci-blocks of 32; per ci-block 9 taps (+1 for the 1x1) each one
// 16x16x32 K-step.  BN folded into weights (A) and cconst epilogue constant.
// LDS: input rows h-1..h+1 transposed to [row][w_slot][ci], CIP=34 pad.
// ---------------------------------------------------------------------------
__global__ __launch_bounds__(256) void conv_mfma(
    const __hip_bfloat16* __restrict__ xin,
    const __hip_bfloat16* __restrict__ xidc,
    const __hip_bfloat16* __restrict__ wrep,
    const __hip_bfloat16* __restrict__ wrepi,
    const float* __restrict__ cconst,
    void* __restrict__ outp,
    int has_idc, int out_bf16)
{
    __shared__ short xs[3 * 130 * 34];     // 3 input rows, slot=w+1, ci-contig
    __shared__ short xs2[130 * 34];        // idc center row

    const int tid = threadIdx.x;
    const int l  = tid & 63;
    const int wv = tid >> 6;
    const int wave_co = (wv & 1) * 64;
    const int wave_w  = (wv >> 1) * 64;
    const int g = blockIdx.x & 1;
    const int h = (blockIdx.x >> 1) & 255;
    const int n = blockIdx.x >> 9;
    const int lq = l >> 4;     // quad
    const int lm = l & 15;

    f32x4 acc[4][4];
    #pragma unroll
    for (int a = 0; a < 4; a++)
        #pragma unroll
        for (int b = 0; b < 4; b++) acc[a][b] = (f32x4)0.0f;

    const int npairs = has_idc ? 128 : 96;
    const int ntaps  = has_idc ? 10 : 9;

    for (int cb = 0; cb < 8; cb++) {
        __syncthreads();
        // ---- stage 32 ci x 3 rows (+ idc center row) into LDS, transposed
        for (int p = wv * 2 + (l >> 5); p < npairs; p += 8) {
            int row = p >> 5;
            int ci  = p & 31;
            int w4  = (l & 31) * 4;
            unsigned u0 = 0, u1 = 0;
            short* dst;
            if (row < 3) {
                int hh = h - 1 + row;
                if (0 <= hh && hh < 256) {
                    const unsigned* gp = (const unsigned*)(xin +
                        ((((size_t)n * 256 + cb * 32 + ci) * 256 + hh) << 7) + w4);
                    u0 = gp[0]; u1 = gp[1];
                }
                dst = xs + (row * 130 + w4 + 1) * 34 + ci;
            } else {
                const unsigned* gp = (const unsigned*)(xidc +
                    ((((size_t)n * 256 + cb * 32 + ci) * 256 + h) << 7) + w4);
                u0 = gp[0]; u1 = gp[1];
                dst = xs2 + (w4 + 1) * 34 + ci;
            }
            dst[0]   = (short)(u0 & 0xFFFF);
            dst[34]  = (short)(u0 >> 16);
            dst[68]  = (short)(u1 & 0xFFFF);
            dst[102] = (short)(u1 >> 16);
        }
        // zero the w-halo columns (slots 0 and 129) of the 3 conv rows
        if (tid < 192) {
            int row = tid >> 6;
            int side = (tid >> 5) & 1;
            int ci = tid & 31;
            xs[(row * 130 + (side ? 129 : 0)) * 34 + ci] = 0;
        }
        __syncthreads();

        // ---- K-steps: 9 taps (+1 idc) x 32 ci
        for (int tap = 0; tap < ntaps; tap++) {
            const __hip_bfloat16* ap;
            const short* bs;
            if (tap < 9) {
                int kh = tap / 3;
                int kw = tap - kh * 3;
                ap = wrep + (((size_t)(g * 8 + cb) * 9 + tap) * 128) * 32;
                bs = xs + (kh * 130 + wave_w + kw) * 34;
            } else {
                ap = wrepi + ((size_t)(g * 8 + cb) * 128) * 32;
                bs = xs2 + (wave_w + 1) * 34;
            }
            short8 afr[4];
            #pragma unroll
            for (int cs = 0; cs < 4; cs++) {
                const int4v* p4 = (const int4v*)(ap + (size_t)(wave_co + cs * 16 + lm) * 32 + lq * 8);
                afr[cs] = __builtin_bit_cast(short8, *p4);
            }
            #pragma unroll
            for (int ws = 0; ws < 4; ws++) {
                const int* ip = (const int*)(bs + (ws * 16 + lm) * 34 + lq * 8);
                int4v bv;
                bv.x = ip[0]; bv.y = ip[1]; bv.z = ip[2]; bv.w = ip[3];
                short8 bfr = __builtin_bit_cast(short8, bv);
                #pragma unroll
                for (int cs = 0; cs < 4; cs++) {
                    acc[cs][ws] = __builtin_amdgcn_mfma_f32_16x16x32_bf16(
                        afr[cs], bfr, acc[cs][ws], 0, 0, 0);
                }
            }
        }
    }

    // ---- epilogue: + folded-BN constant, ReLU, store (bf16 or fp32)
    #pragma unroll
    for (int cs = 0; cs < 4; cs++) {
        #pragma unroll
        for (int r = 0; r < 4; r++) {
            int co_g = g * 128 + wave_co + cs * 16 + lq * 4 + r;
            float cc = cconst[co_g];
            #pragma unroll
            for (int ws = 0; ws < 4; ws++) {
                float v = acc[cs][ws][r] + cc;
                v = fmaxf(v, 0.f);
                size_t oidx = (((size_t)n * 256 + co_g) * 256 + h) * 128 + wave_w + ws * 16 + lm;
                if (out_bf16) ((__hip_bfloat16*)outp)[oidx] = __float2bfloat16(v);
                else          ((float*)outp)[oidx] = v;
            }
        }
    }
}

// ---------------------------------------------------------------------------
extern "C" void kernel_launch(void* const* d_in, const int* in_sizes, int n_in,
                              void* d_out, int out_size, void* d_ws, size_t ws_size,
                              hipStream_t stream) {
    const float* x       = (const float*)d_in[0];
    const float* qkv_w   = (const float*)d_in[1];
    const float* qkv_b   = (const float*)d_in[2];
    const float* proj_w  = (const float*)d_in[3];
    const float* proj_b  = (const float*)d_in[4];
    const float* rpb     = (const float*)d_in[5];
    const float* conv1_w = (const float*)d_in[6];
    const float* conv1_b = (const float*)d_in[7];
    const float* bn1_g   = (const float*)d_in[8];
    const float* bn1_b   = (const float*)d_in[9];
    const float* bn1_m   = (const float*)d_in[10];
    const float* bn1_v   = (const float*)d_in[11];
    const float* conv2_w = (const float*)d_in[12];
    const float* conv2_b = (const float*)d_in[13];
    const float* bn2_g   = (const float*)d_in[14];
    const float* bn2_b   = (const float*)d_in[15];
    const float* bn2_m   = (const float*)d_in[16];
    const float* bn2_v   = (const float*)d_in[17];
    const float* idc_w   = (const float*)d_in[18];
    const float* idc_b   = (const float*)d_in[19];
    const float* bni_g   = (const float*)d_in[20];
    const float* bni_b   = (const float*)d_in[21];
    const float* bni_m   = (const float*)d_in[22];
    const float* bni_v   = (const float*)d_in[23];

    const size_t TE = (size_t)BATCH * 256 * 256 * 128;    // 33,554,432
    char* ws = (char*)d_ws;
    __hip_bfloat16* xatt  = (__hip_bfloat16*)(ws);
    __hip_bfloat16* y1    = (__hip_bfloat16*)(ws + TE * 2);
    __hip_bfloat16* wrep1 = (__hip_bfloat16*)(ws + TE * 4);
    __hip_bfloat16* wrep2 = (__hip_bfloat16*)(ws + TE * 4 + 1179648);
    __hip_bfloat16* wrepi = (__hip_bfloat16*)(ws + TE * 4 + 2359296);
    float*          c1    = (float*)(ws + TE * 4 + 2490368);
    float*          c2    = (float*)(ws + TE * 4 + 2491392);

    repack3<<<2304, 256, 0, stream>>>(conv1_w, conv1_b, bn1_g, bn1_b, bn1_m, bn1_v, wrep1, c1);
    repack3<<<2304, 256, 0, stream>>>(conv2_w, conv2_b, bn2_g, bn2_b, bn2_m, bn2_v, wrep2, c2);
    repack1<<<256, 256, 0, stream>>>(idc_w, idc_b, bni_g, bni_b, bni_m, bni_v, wrepi, c2);

    attn_kernel<<<16384, 256, 0, stream>>>(x, qkv_w, qkv_b, proj_w, proj_b, rpb, xatt);

    conv_mfma<<<2048, 256, 0, stream>>>(xatt, nullptr, wrep1, nullptr, c1, (void*)y1, 0, 1);
    conv_mfma<<<2048, 256, 0, stream>>>(y1, xatt, wrep2, wrepi, c2, d_out, 1, 0);
}

// Round 3
// 959.269 us; speedup vs baseline: 38.1274x; 1.7444x over previous
//
#include <hip/hip_runtime.h>
#include <hip/hip_bf16.h>
#include <math.h>
#include <cstddef>

// Problem constants
#define BATCH 4
#define WDIM 256
#define CDIM 128
#define WS 4
#define SHIFT 3
#define HEADS 4
#define HD 32
#define NTOK 16

typedef __attribute__((ext_vector_type(8))) short short8;
typedef __attribute__((ext_vector_type(4))) int int4v;
typedef __attribute__((ext_vector_type(4))) float f32x4;

__device__ __forceinline__ int regionOf(int v) {
    return v < (WDIM - WS) ? 0 : (v < (WDIM - SHIFT) ? 1 : 2);
}

__device__ __forceinline__ short f2bf(float v) {
    __hip_bfloat16 h = __float2bfloat16(v);
    return __builtin_bit_cast(short, h);
}
__device__ __forceinline__ float bf2f(short s) {
    unsigned u = ((unsigned)(unsigned short)s) << 16;
    return __builtin_bit_cast(float, u);
}

// ---------------------------------------------------------------------------
// Repack attention weights: [c][j] fp32 -> [j][c] bf16 (MFMA A-operand order)
// ---------------------------------------------------------------------------
__global__ __launch_bounds__(256) void repack_attnw(
    const float* __restrict__ qkv_w,   // (128, 384)
    const float* __restrict__ proj_w,  // (128, 128)
    __hip_bfloat16* __restrict__ qkvw_rep,   // (384, 128)
    __hip_bfloat16* __restrict__ projw_rep)  // (128, 128)
{
    int idx = blockIdx.x * 256 + threadIdx.x;   // < 65536
    if (idx < 49152) {
        int j = idx >> 7, c = idx & 127;
        qkvw_rep[idx] = __float2bfloat16(qkv_w[c * 384 + j]);
    } else {
        int k = idx - 49152;
        int j = k >> 7, c = k & 127;
        projw_rep[k] = __float2bfloat16(proj_w[c * 128 + j]);
    }
}

// ---------------------------------------------------------------------------
// Kernel A: fused upsample + shifted-window MSA + residual, MFMA version.
// One block = 2 windows (32 tokens), 256 threads = 4 waves.
// LDS layout (bytes):
//   qkvs  [32][264] bf16   @ 0      (16896)  | aliases xrow [32][2][64] f32 (16384)
//   Xb    [32][136] bf16   @ 16896  (8704)
//   Ps    [2][4][16][24]   @ 25600  (6144)
//   Vt    [2][128][24]     @ 31744  (12288)
//   aout  [32][136] bf16   @ 44032  (8704)   | reused for final output
//   rpbs  196 f32          @ 52736
//   qkvb  384 f32          @ 53520
//   projb 128 f32          @ 55056
//   tokw2 32 f32           @ 55568
// ---------------------------------------------------------------------------
__global__ __launch_bounds__(256) void attn_kernel(
    const float* __restrict__ xin,
    const __hip_bfloat16* __restrict__ qkvw_rep,
    const __hip_bfloat16* __restrict__ projw_rep,
    const float* __restrict__ qkv_b,
    const float* __restrict__ proj_b,
    const float* __restrict__ rpb,
    __hip_bfloat16* __restrict__ xatt)
{
    __shared__ __align__(16) char smem[55696];
    short* qkvs  = (short*)smem;                       // [tok][264]
    float (*xrow)[2][64] = (float(*)[2][64])smem;      // aliases qkvs
    short* Xb    = (short*)(smem + 16896);             // [tok][136]
    short* Ps    = (short*)(smem + 25600);             // [(w*4+h)*16+n][24]
    short* Vt    = (short*)(smem + 31744);             // [w*128+d][24]
    short* aoutS = (short*)(smem + 44032);             // [tok][136]
    float* rpbs  = (float*)(smem + 52736);
    float* qkvbS = (float*)(smem + 53520);
    float* projbS= (float*)(smem + 55056);
    float* tokw2 = (float*)(smem + 55568);

    const int tid = threadIdx.x;
    const int bid = blockIdx.x;
    const int l   = tid & 63;
    const int wv  = tid >> 6;
    const int lm  = l & 15;
    const int lq  = l >> 4;

    // ---- preload small tables -------------------------------------------
    if (tid < 196) rpbs[tid] = rpb[tid];
    for (int i = tid; i < 384; i += 256) qkvbS[i] = qkv_b[i];
    if (tid < 128) projbS[tid] = proj_b[tid];

    // ---- Stage 1: load raw rows (2 per token) ---------------------------
    #pragma unroll
    for (int k = 0; k < 4; k++) {
        int id = tid + k * 256;          // 0..1023
        int n   = id >> 5;               // token 0..31
        int row = (id >> 4) & 1;
        int ll  = id & 15;
        int w_  = n >> 4, nn = n & 15;
        int win = bid * 2 + w_;
        int b   = win >> 12;
        int wh  = (win >> 6) & 63;
        int ww  = win & 63;
        int r = nn >> 2, c = nn & 3;
        int gh = (wh * 4 + r + SHIFT) & 255;
        int gw = (ww * 4 + c + SHIFT) & 255;
        float pos2 = gw * (127.0f / 255.0f);
        int lo2 = (int)floorf(pos2);
        int hi2 = min(lo2 + 1, 127);
        if (row == 0 && ll == 0) tokw2[n] = pos2 - (float)lo2;
        int src = row == 0 ? lo2 : hi2;
        const float4* rp = (const float4*)(xin + (((size_t)b * 256 + gh) * 128 + src) * 64);
        ((float4*)&xrow[n][row][0])[ll] = rp[ll];
    }
    __syncthreads();

    // ---- Stage 2: interp along last axis -> Xb bf16 ---------------------
    {
        int n = tid >> 3;
        int jj = tid & 7;
        float w2 = tokw2[n];
        #pragma unroll
        for (int i = 0; i < 16; i++) {
            int cc = jj * 16 + i;
            float pos3 = cc * (63.0f / 127.0f);
            int lo3 = (int)floorf(pos3);
            int hi3 = min(lo3 + 1, 63);
            float w3 = pos3 - (float)lo3;
            float v0 = xrow[n][0][lo3] * (1.f - w3) + xrow[n][0][hi3] * w3;
            float v1 = xrow[n][1][lo3] * (1.f - w3) + xrow[n][1][hi3] * w3;
            Xb[n * 136 + cc] = f2bf(v0 * (1.f - w2) + v1 * w2);
        }
    }
    __syncthreads();

    // ---- Stage 3: QKV GEMM (M=384 j, N=32 tok, K=128) -------------------
    {
        f32x4 qacc[6][2];
        #pragma unroll
        for (int a = 0; a < 6; a++)
            #pragma unroll
            for (int t = 0; t < 2; t++) qacc[a][t] = (f32x4)0.0f;

        for (int ks = 0; ks < 4; ks++) {
            short8 af[6];
            #pragma unroll
            for (int jj = 0; jj < 6; jj++) {
                const int4v* gp = (const int4v*)(qkvw_rep +
                    (size_t)(wv * 96 + jj * 16 + lm) * 128 + ks * 32 + lq * 8);
                af[jj] = __builtin_bit_cast(short8, *gp);
            }
            short8 bfr[2];
            #pragma unroll
            for (int tt = 0; tt < 2; tt++) {
                bfr[tt] = *(const short8*)&Xb[(tt * 16 + lm) * 136 + ks * 32 + lq * 8];
            }
            #pragma unroll
            for (int jj = 0; jj < 6; jj++)
                #pragma unroll
                for (int tt = 0; tt < 2; tt++)
                    qacc[jj][tt] = __builtin_amdgcn_mfma_f32_16x16x32_bf16(
                        af[jj], bfr[tt], qacc[jj][tt], 0, 0, 0);
        }
        // epilogue: bias (+scale for Q), write to qkvs / Vt
        #pragma unroll
        for (int jj = 0; jj < 6; jj++) {
            int jbase = wv * 96 + jj * 16 + lq * 4;
            #pragma unroll
            for (int tt = 0; tt < 2; tt++) {
                int tok = tt * 16 + lm;
                if (jbase < 128) {
                    float v0 = (qacc[jj][tt][0] + qkvbS[jbase+0]) * 0.17677669529663687f;
                    float v1 = (qacc[jj][tt][1] + qkvbS[jbase+1]) * 0.17677669529663687f;
                    float v2 = (qacc[jj][tt][2] + qkvbS[jbase+2]) * 0.17677669529663687f;
                    float v3 = (qacc[jj][tt][3] + qkvbS[jbase+3]) * 0.17677669529663687f;
                    unsigned p0 = (unsigned short)f2bf(v0) | ((unsigned)(unsigned short)f2bf(v1) << 16);
                    unsigned p1 = (unsigned short)f2bf(v2) | ((unsigned)(unsigned short)f2bf(v3) << 16);
                    *(unsigned*)&qkvs[tok * 264 + jbase]     = p0;
                    *(unsigned*)&qkvs[tok * 264 + jbase + 2] = p1;
                } else if (jbase < 256) {
                    float v0 = qacc[jj][tt][0] + qkvbS[jbase+0];
                    float v1 = qacc[jj][tt][1] + qkvbS[jbase+1];
                    float v2 = qacc[jj][tt][2] + qkvbS[jbase+2];
                    float v3 = qacc[jj][tt][3] + qkvbS[jbase+3];
                    unsigned p0 = (unsigned short)f2bf(v0) | ((unsigned)(unsigned short)f2bf(v1) << 16);
                    unsigned p1 = (unsigned short)f2bf(v2) | ((unsigned)(unsigned short)f2bf(v3) << 16);
                    *(unsigned*)&qkvs[tok * 264 + jbase]     = p0;
                    *(unsigned*)&qkvs[tok * 264 + jbase + 2] = p1;
                } else {
                    #pragma unroll
                    for (int r = 0; r < 4; r++) {
                        int d = jbase - 256 + r;
                        Vt[(tt * 128 + d) * 24 + lm] = f2bf(qacc[jj][tt][r] + qkvbS[jbase + r]);
                    }
                }
            }
        }
    }
    __syncthreads();

    // ---- Stage 4: scores + bias + mask + softmax (per wave: 1 win, 2 h) -
    {
        int w_ = wv >> 1;
        int hb = (wv & 1) * 2;
        int win = bid * 2 + w_;
        int wh = (win >> 6) & 63;
        int ww = win & 63;
        int m  = lm;
        int r2 = m >> 2, c2 = m & 3;
        int reg2 = regionOf(wh * 4 + r2) * 3 + regionOf(ww * 4 + c2);
        #pragma unroll
        for (int hh = 0; hh < 2; hh++) {
            int h = hb + hh;
            short8 qa = *(const short8*)&qkvs[(w_ * 16 + lm) * 264 + h * 32 + lq * 8];
            short8 kb = *(const short8*)&qkvs[(w_ * 16 + lm) * 264 + 128 + h * 32 + lq * 8];
            f32x4 s = __builtin_amdgcn_mfma_f32_16x16x32_bf16(qa, kb, (f32x4)0.0f, 0, 0, 0);
            #pragma unroll
            for (int r = 0; r < 4; r++) {
                int n = lq * 4 + r;
                int r1 = n >> 2, c1 = n & 3;
                int ridx = (r1 - r2 + 3) * 7 + (c1 - c2 + 3);
                float v = s[r] + rpbs[ridx * 4 + h];
                int reg1 = regionOf(wh * 4 + r1) * 3 + regionOf(ww * 4 + c1);
                if (reg1 != reg2) v -= 100.f;
                // softmax over m (lanes lm within 16-group)
                float mx = v;
                mx = fmaxf(mx, __shfl_xor(mx, 1));
                mx = fmaxf(mx, __shfl_xor(mx, 2));
                mx = fmaxf(mx, __shfl_xor(mx, 4));
                mx = fmaxf(mx, __shfl_xor(mx, 8));
                float e = __expf(v - mx);
                float ss = e;
                ss += __shfl_xor(ss, 1);
                ss += __shfl_xor(ss, 2);
                ss += __shfl_xor(ss, 4);
                ss += __shfl_xor(ss, 8);
                Ps[((w_ * 4 + h) * 16 + n) * 24 + m] = f2bf(e / ss);
            }
        }
    }
    __syncthreads();

    // ---- Stage 5: PV (zero-padded K=32 MFMA) ----------------------------
    {
        int w_ = wv >> 1;
        int hb = (wv & 1) * 2;
        #pragma unroll
        for (int hh = 0; hh < 2; hh++) {
            int h = hb + hh;
            #pragma unroll
            for (int dt = 0; dt < 2; dt++) {
                short8 pa = (short8)0;
                short8 vb = (short8)0;
                if (lq < 2) {
                    pa = *(const short8*)&Ps[((w_ * 4 + h) * 16 + lm) * 24 + lq * 8];
                    vb = *(const short8*)&Vt[(w_ * 128 + h * 32 + dt * 16 + lm) * 24 + lq * 8];
                }
                f32x4 o = __builtin_amdgcn_mfma_f32_16x16x32_bf16(pa, vb, (f32x4)0.0f, 0, 0, 0);
                #pragma unroll
                for (int r = 0; r < 4; r++) {
                    aoutS[(w_ * 16 + lq * 4 + r) * 136 + h * 32 + dt * 16 + lm] = f2bf(o[r]);
                }
            }
        }
    }
    __syncthreads();

    // ---- Stage 6: proj GEMM (M=128 j, N=32 tok, K=128) + shortcut -------
    {
        f32x4 cacc[2][2];
        #pragma unroll
        for (int a = 0; a < 2; a++)
            #pragma unroll
            for (int t = 0; t < 2; t++) cacc[a][t] = (f32x4)0.0f;

        for (int ks = 0; ks < 4; ks++) {
            short8 af[2];
            #pragma unroll
            for (int jj = 0; jj < 2; jj++) {
                const int4v* gp = (const int4v*)(projw_rep +
                    (size_t)(wv * 32 + jj * 16 + lm) * 128 + ks * 32 + lq * 8);
                af[jj] = __builtin_bit_cast(short8, *gp);
            }
            short8 bfr[2];
            #pragma unroll
            for (int tt = 0; tt < 2; tt++)
                bfr[tt] = *(const short8*)&aoutS[(tt * 16 + lm) * 136 + ks * 32 + lq * 8];
            #pragma unroll
            for (int jj = 0; jj < 2; jj++)
                #pragma unroll
                for (int tt = 0; tt < 2; tt++)
                    cacc[jj][tt] = __builtin_amdgcn_mfma_f32_16x16x32_bf16(
                        af[jj], bfr[tt], cacc[jj][tt], 0, 0, 0);
        }
        __syncthreads();   // all waves done reading aout; reuse it for final
        #pragma unroll
        for (int jj = 0; jj < 2; jj++) {
            int jbase = wv * 32 + jj * 16 + lq * 4;
            #pragma unroll
            for (int tt = 0; tt < 2; tt++) {
                int tok = tt * 16 + lm;
                float v0 = cacc[jj][tt][0] + projbS[jbase+0] + bf2f(Xb[tok * 136 + jbase+0]);
                float v1 = cacc[jj][tt][1] + projbS[jbase+1] + bf2f(Xb[tok * 136 + jbase+1]);
                float v2 = cacc[jj][tt][2] + projbS[jbase+2] + bf2f(Xb[tok * 136 + jbase+2]);
                float v3 = cacc[jj][tt][3] + projbS[jbase+3] + bf2f(Xb[tok * 136 + jbase+3]);
                unsigned p0 = (unsigned short)f2bf(v0) | ((unsigned)(unsigned short)f2bf(v1) << 16);
                unsigned p1 = (unsigned short)f2bf(v2) | ((unsigned)(unsigned short)f2bf(v3) << 16);
                *(unsigned*)&aoutS[tok * 136 + jbase]     = p0;
                *(unsigned*)&aoutS[tok * 136 + jbase + 2] = p1;
            }
        }
    }
    __syncthreads();

    // ---- Stage 7: coalesced store --------------------------------------
    {
        int row  = tid >> 3;       // token 0..31
        int part = tid & 7;        // 16-ch chunk
        int w_ = row >> 4, nn = row & 15;
        int win = bid * 2 + w_;
        int b   = win >> 12;
        int wh  = (win >> 6) & 63;
        int ww  = win & 63;
        int r = nn >> 2, c = nn & 3;
        int gh = (wh * 4 + r + SHIFT) & 255;
        int gw = (ww * 4 + c + SHIFT) & 255;
        size_t base = (((size_t)b * 256 + gh) * 256 + gw) * 128 + part * 16;
        int4v d0 = *(const int4v*)&aoutS[row * 136 + part * 16];
        int4v d1 = *(const int4v*)&aoutS[row * 136 + part * 16 + 8];
        *(int4v*)(xatt + base)     = d0;
        *(int4v*)(xatt + base + 8) = d1;
    }
}

// ---------------------------------------------------------------------------
// Weight repack for convs: fold BN scale, fp32 -> bf16, per-tap layout.
// ---------------------------------------------------------------------------
__global__ __launch_bounds__(256) void repack3(
    const float* __restrict__ w, const float* __restrict__ bias,
    const float* __restrict__ g_, const float* __restrict__ b_,
    const float* __restrict__ m_, const float* __restrict__ v_,
    __hip_bfloat16* __restrict__ wrep, float* __restrict__ cconst)
{
    int idx = blockIdx.x * 256 + threadIdx.x;       // < 589824
    int co = idx / 2304;
    int rem = idx - co * 2304;
    int ci = rem / 9;
    int tap = rem - ci * 9;
    float s = g_[co] * rsqrtf(v_[co] + 1e-5f);
    size_t o = ((((size_t)(co >> 7) * 8 + (ci >> 5)) * 9 + tap) * 128 + (co & 127)) * 32 + (ci & 31);
    wrep[o] = __float2bfloat16(w[idx] * s);
    if (rem == 0) cconst[co] = bias[co] * s + (b_[co] - m_[co] * s);
}

__global__ __launch_bounds__(256) void repack1(
    const float* __restrict__ w, const float* __restrict__ bias,
    const float* __restrict__ g_, const float* __restrict__ b_,
    const float* __restrict__ m_, const float* __restrict__ v_,
    __hip_bfloat16* __restrict__ wrep, float* __restrict__ cconst)
{
    int idx = blockIdx.x * 256 + threadIdx.x;       // < 65536
    int co = idx >> 8, ci = idx & 255;
    float s = g_[co] * rsqrtf(v_[co] + 1e-5f);
    wrep[(((size_t)(co >> 7) * 8 + (ci >> 5)) * 128 + (co & 127)) * 32 + (ci & 31)] =
        __float2bfloat16(w[idx] * s);
    if (ci == 0) cconst[co] += bias[co] * s + (b_[co] - m_[co] * s);
}

// ---------------------------------------------------------------------------
// MFMA implicit-GEMM 3x3 conv (+ optional fused 1x1 identity branch).
// ---------------------------------------------------------------------------
__global__ __launch_bounds__(256) void conv_mfma(
    const __hip_bfloat16* __restrict__ xin,
    const __hip_bfloat16* __restrict__ xidc,
    const __hip_bfloat16* __restrict__ wrep,
    const __hip_bfloat16* __restrict__ wrepi,
    const float* __restrict__ cconst,
    void* __restrict__ outp,
    int has_idc, int out_bf16)
{
    __shared__ short xs[3 * 130 * 34];
    __shared__ short xs2[130 * 34];

    const int tid = threadIdx.x;
    const int l  = tid & 63;
    const int wv = tid >> 6;
    const int wave_co = (wv & 1) * 64;
    const int wave_w  = (wv >> 1) * 64;
    const int g = blockIdx.x & 1;
    const int h = (blockIdx.x >> 1) & 255;
    const int n = blockIdx.x >> 9;
    const int lq = l >> 4;
    const int lm = l & 15;

    f32x4 acc[4][4];
    #pragma unroll
    for (int a = 0; a < 4; a++)
        #pragma unroll
        for (int b = 0; b < 4; b++) acc[a][b] = (f32x4)0.0f;

    const int npairs = has_idc ? 128 : 96;
    const int ntaps  = has_idc ? 10 : 9;

    for (int cb = 0; cb < 8; cb++) {
        __syncthreads();
        for (int p = wv * 2 + (l >> 5); p < npairs; p += 8) {
            int row = p >> 5;
            int ci  = p & 31;
            int w4  = (l & 31) * 4;
            unsigned u0 = 0, u1 = 0;
            short* dst;
            if (row < 3) {
                int hh = h - 1 + row;
                if (0 <= hh && hh < 256) {
                    const unsigned* gp = (const unsigned*)(xin +
                        ((((size_t)n * 256 + cb * 32 + ci) * 256 + hh) << 7) + w4);
                    u0 = gp[0]; u1 = gp[1];
                }
                dst = xs + (row * 130 + w4 + 1) * 34 + ci;
            } else {
                const unsigned* gp = (const unsigned*)(xidc +
                    ((((size_t)n * 256 + cb * 32 + ci) * 256 + h) << 7) + w4);
                u0 = gp[0]; u1 = gp[1];
                dst = xs2 + (w4 + 1) * 34 + ci;
            }
            dst[0]   = (short)(u0 & 0xFFFF);
            dst[34]  = (short)(u0 >> 16);
            dst[68]  = (short)(u1 & 0xFFFF);
            dst[102] = (short)(u1 >> 16);
        }
        if (tid < 192) {
            int row = tid >> 6;
            int side = (tid >> 5) & 1;
            int ci = tid & 31;
            xs[(row * 130 + (side ? 129 : 0)) * 34 + ci] = 0;
        }
        __syncthreads();

        for (int tap = 0; tap < ntaps; tap++) {
            const __hip_bfloat16* ap;
            const short* bs;
            if (tap < 9) {
                int kh = tap / 3;
                int kw = tap - kh * 3;
                ap = wrep + (((size_t)(g * 8 + cb) * 9 + tap) * 128) * 32;
                bs = xs + (kh * 130 + wave_w + kw) * 34;
            } else {
                ap = wrepi + ((size_t)(g * 8 + cb) * 128) * 32;
                bs = xs2 + (wave_w + 1) * 34;
            }
            short8 afr[4];
            #pragma unroll
            for (int cs = 0; cs < 4; cs++) {
                const int4v* p4 = (const int4v*)(ap + (size_t)(wave_co + cs * 16 + lm) * 32 + lq * 8);
                afr[cs] = __builtin_bit_cast(short8, *p4);
            }
            #pragma unroll
            for (int ws = 0; ws < 4; ws++) {
                const int* ip = (const int*)(bs + (ws * 16 + lm) * 34 + lq * 8);
                int4v bv;
                bv.x = ip[0]; bv.y = ip[1]; bv.z = ip[2]; bv.w = ip[3];
                short8 bfr = __builtin_bit_cast(short8, bv);
                #pragma unroll
                for (int cs = 0; cs < 4; cs++) {
                    acc[cs][ws] = __builtin_amdgcn_mfma_f32_16x16x32_bf16(
                        afr[cs], bfr, acc[cs][ws], 0, 0, 0);
                }
            }
        }
    }

    #pragma unroll
    for (int cs = 0; cs < 4; cs++) {
        #pragma unroll
        for (int r = 0; r < 4; r++) {
            int co_g = g * 128 + wave_co + cs * 16 + lq * 4 + r;
            float cc = cconst[co_g];
            #pragma unroll
            for (int ws = 0; ws < 4; ws++) {
                float v = acc[cs][ws][r] + cc;
                v = fmaxf(v, 0.f);
                size_t oidx = (((size_t)n * 256 + co_g) * 256 + h) * 128 + wave_w + ws * 16 + lm;
                if (out_bf16) ((__hip_bfloat16*)outp)[oidx] = __float2bfloat16(v);
                else          ((float*)outp)[oidx] = v;
            }
        }
    }
}

// ---------------------------------------------------------------------------
extern "C" void kernel_launch(void* const* d_in, const int* in_sizes, int n_in,
                              void* d_out, int out_size, void* d_ws, size_t ws_size,
                              hipStream_t stream) {
    const float* x       = (const float*)d_in[0];
    const float* qkv_w   = (const float*)d_in[1];
    const float* qkv_b   = (const float*)d_in[2];
    const float* proj_w  = (const float*)d_in[3];
    const float* proj_b  = (const float*)d_in[4];
    const float* rpb     = (const float*)d_in[5];
    const float* conv1_w = (const float*)d_in[6];
    const float* conv1_b = (const float*)d_in[7];
    const float* bn1_g   = (const float*)d_in[8];
    const float* bn1_b   = (const float*)d_in[9];
    const float* bn1_m   = (const float*)d_in[10];
    const float* bn1_v   = (const float*)d_in[11];
    const float* conv2_w = (const float*)d_in[12];
    const float* conv2_b = (const float*)d_in[13];
    const float* bn2_g   = (const float*)d_in[14];
    const float* bn2_b   = (const float*)d_in[15];
    const float* bn2_m   = (const float*)d_in[16];
    const float* bn2_v   = (const float*)d_in[17];
    const float* idc_w   = (const float*)d_in[18];
    const float* idc_b   = (const float*)d_in[19];
    const float* bni_g   = (const float*)d_in[20];
    const float* bni_b   = (const float*)d_in[21];
    const float* bni_m   = (const float*)d_in[22];
    const float* bni_v   = (const float*)d_in[23];

    const size_t TE = (size_t)BATCH * 256 * 256 * 128;    // 33,554,432
    char* ws = (char*)d_ws;
    __hip_bfloat16* xatt  = (__hip_bfloat16*)(ws);
    __hip_bfloat16* y1    = (__hip_bfloat16*)(ws + TE * 2);
    __hip_bfloat16* wrep1 = (__hip_bfloat16*)(ws + TE * 4);
    __hip_bfloat16* wrep2 = (__hip_bfloat16*)(ws + TE * 4 + 1179648);
    __hip_bfloat16* wrepi = (__hip_bfloat16*)(ws + TE * 4 + 2359296);
    float*          c1    = (float*)(ws + TE * 4 + 2490368);
    float*          c2    = (float*)(ws + TE * 4 + 2491392);
    __hip_bfloat16* qkvw_rep = (__hip_bfloat16*)(ws + TE * 4 + 2492416);
    __hip_bfloat16* projw_rep= (__hip_bfloat16*)(ws + TE * 4 + 2590720);

    repack3<<<2304, 256, 0, stream>>>(conv1_w, conv1_b, bn1_g, bn1_b, bn1_m, bn1_v, wrep1, c1);
    repack3<<<2304, 256, 0, stream>>>(conv2_w, conv2_b, bn2_g, bn2_b, bn2_m, bn2_v, wrep2, c2);
    repack1<<<256, 256, 0, stream>>>(idc_w, idc_b, bni_g, bni_b, bni_m, bni_v, wrepi, c2);
    repack_attnw<<<256, 256, 0, stream>>>(qkv_w, proj_w, qkvw_rep, projw_rep);

    attn_kernel<<<8192, 256, 0, stream>>>(x, qkvw_rep, projw_rep, qkv_b, proj_b, rpb, xatt);

    conv_mfma<<<2048, 256, 0, stream>>>(xatt, nullptr, wrep1, nullptr, c1, (void*)y1, 0, 1);
    conv_mfma<<<2048, 256, 0, stream>>>(y1, xatt, wrep2, wrepi, c2, d_out, 1, 0);
}

// Round 4
// 837.043 us; speedup vs baseline: 43.6948x; 1.1460x over previous
//
#include <hip/hip_runtime.h>
#include <hip/hip_bf16.h>
#include <math.h>
#include <cstddef>

// Problem constants
#define BATCH 4
#define WDIM 256
#define CDIM 128
#define WS 4
#define SHIFT 3
#define HEADS 4
#define HD 32
#define NTOK 16

typedef __attribute__((ext_vector_type(8))) short short8;
typedef __attribute__((ext_vector_type(4))) int int4v;
typedef __attribute__((ext_vector_type(4))) float f32x4;

__device__ __forceinline__ int regionOf(int v) {
    return v < (WDIM - WS) ? 0 : (v < (WDIM - SHIFT) ? 1 : 2);
}

__device__ __forceinline__ short f2bf(float v) {
    __hip_bfloat16 h = __float2bfloat16(v);
    return __builtin_bit_cast(short, h);
}
__device__ __forceinline__ float bf2f(short s) {
    unsigned u = ((unsigned)(unsigned short)s) << 16;
    return __builtin_bit_cast(float, u);
}

// ---------------------------------------------------------------------------
// Repack attention weights: [c][j] fp32 -> [j][c] bf16 (MFMA A-operand order)
// ---------------------------------------------------------------------------
__global__ __launch_bounds__(256) void repack_attnw(
    const float* __restrict__ qkv_w,   // (128, 384)
    const float* __restrict__ proj_w,  // (128, 128)
    __hip_bfloat16* __restrict__ qkvw_rep,   // (384, 128)
    __hip_bfloat16* __restrict__ projw_rep)  // (128, 128)
{
    int idx = blockIdx.x * 256 + threadIdx.x;   // < 65536
    if (idx < 49152) {
        int j = idx >> 7, c = idx & 127;
        qkvw_rep[idx] = __float2bfloat16(qkv_w[c * 384 + j]);
    } else {
        int k = idx - 49152;
        int j = k >> 7, c = k & 127;
        projw_rep[k] = __float2bfloat16(proj_w[c * 128 + j]);
    }
}

// ---------------------------------------------------------------------------
// Kernel A: fused upsample + shifted-window MSA + residual, MFMA version.
// One block = 2 windows (32 tokens), 256 threads = 4 waves.
// Output layout: NHWC with rolled channel slot: xatt[((b,gw),j), (gh+1)&255]
// ---------------------------------------------------------------------------
__global__ __launch_bounds__(256) void attn_kernel(
    const float* __restrict__ xin,
    const __hip_bfloat16* __restrict__ qkvw_rep,
    const __hip_bfloat16* __restrict__ projw_rep,
    const float* __restrict__ qkv_b,
    const float* __restrict__ proj_b,
    const float* __restrict__ rpb,
    __hip_bfloat16* __restrict__ xatt)
{
    __shared__ __align__(16) char smem[55696];
    short* qkvs  = (short*)smem;                       // [tok][264]
    float (*xrow)[2][64] = (float(*)[2][64])smem;      // aliases qkvs
    short* Xb    = (short*)(smem + 16896);             // [tok][136]
    short* Ps    = (short*)(smem + 25600);             // [(w*4+h)*16+n][24]
    short* Vt    = (short*)(smem + 31744);             // [w*128+d][24]
    short* aoutS = (short*)(smem + 44032);             // [tok][136]
    float* rpbs  = (float*)(smem + 52736);
    float* qkvbS = (float*)(smem + 53520);
    float* projbS= (float*)(smem + 55056);
    float* tokw2 = (float*)(smem + 55568);

    const int tid = threadIdx.x;
    const int bid = blockIdx.x;
    const int l   = tid & 63;
    const int wv  = tid >> 6;
    const int lm  = l & 15;
    const int lq  = l >> 4;

    if (tid < 196) rpbs[tid] = rpb[tid];
    for (int i = tid; i < 384; i += 256) qkvbS[i] = qkv_b[i];
    if (tid < 128) projbS[tid] = proj_b[tid];

    // ---- Stage 1: load raw rows (2 per token) ---------------------------
    #pragma unroll
    for (int k = 0; k < 4; k++) {
        int id = tid + k * 256;
        int n   = id >> 5;
        int row = (id >> 4) & 1;
        int ll  = id & 15;
        int w_  = n >> 4, nn = n & 15;
        int win = bid * 2 + w_;
        int b   = win >> 12;
        int wh  = (win >> 6) & 63;
        int ww  = win & 63;
        int r = nn >> 2, c = nn & 3;
        int gh = (wh * 4 + r + SHIFT) & 255;
        int gw = (ww * 4 + c + SHIFT) & 255;
        float pos2 = gw * (127.0f / 255.0f);
        int lo2 = (int)floorf(pos2);
        int hi2 = min(lo2 + 1, 127);
        if (row == 0 && ll == 0) tokw2[n] = pos2 - (float)lo2;
        int src = row == 0 ? lo2 : hi2;
        const float4* rp = (const float4*)(xin + (((size_t)b * 256 + gh) * 128 + src) * 64);
        ((float4*)&xrow[n][row][0])[ll] = rp[ll];
    }
    __syncthreads();

    // ---- Stage 2: interp along last axis -> Xb bf16 ---------------------
    {
        int n = tid >> 3;
        int jj = tid & 7;
        float w2 = tokw2[n];
        #pragma unroll
        for (int i = 0; i < 16; i++) {
            int cc = jj * 16 + i;
            float pos3 = cc * (63.0f / 127.0f);
            int lo3 = (int)floorf(pos3);
            int hi3 = min(lo3 + 1, 63);
            float w3 = pos3 - (float)lo3;
            float v0 = xrow[n][0][lo3] * (1.f - w3) + xrow[n][0][hi3] * w3;
            float v1 = xrow[n][1][lo3] * (1.f - w3) + xrow[n][1][hi3] * w3;
            Xb[n * 136 + cc] = f2bf(v0 * (1.f - w2) + v1 * w2);
        }
    }
    __syncthreads();

    // ---- Stage 3: QKV GEMM (M=384 j, N=32 tok, K=128) -------------------
    {
        f32x4 qacc[6][2];
        #pragma unroll
        for (int a = 0; a < 6; a++)
            #pragma unroll
            for (int t = 0; t < 2; t++) qacc[a][t] = (f32x4)0.0f;

        for (int ks = 0; ks < 4; ks++) {
            short8 af[6];
            #pragma unroll
            for (int jj = 0; jj < 6; jj++) {
                const int4v* gp = (const int4v*)(qkvw_rep +
                    (size_t)(wv * 96 + jj * 16 + lm) * 128 + ks * 32 + lq * 8);
                af[jj] = __builtin_bit_cast(short8, *gp);
            }
            short8 bfr[2];
            #pragma unroll
            for (int tt = 0; tt < 2; tt++)
                bfr[tt] = *(const short8*)&Xb[(tt * 16 + lm) * 136 + ks * 32 + lq * 8];
            #pragma unroll
            for (int jj = 0; jj < 6; jj++)
                #pragma unroll
                for (int tt = 0; tt < 2; tt++)
                    qacc[jj][tt] = __builtin_amdgcn_mfma_f32_16x16x32_bf16(
                        af[jj], bfr[tt], qacc[jj][tt], 0, 0, 0);
        }
        #pragma unroll
        for (int jj = 0; jj < 6; jj++) {
            int jbase = wv * 96 + jj * 16 + lq * 4;
            #pragma unroll
            for (int tt = 0; tt < 2; tt++) {
                int tok = tt * 16 + lm;
                if (jbase < 128) {
                    float v0 = (qacc[jj][tt][0] + qkvbS[jbase+0]) * 0.17677669529663687f;
                    float v1 = (qacc[jj][tt][1] + qkvbS[jbase+1]) * 0.17677669529663687f;
                    float v2 = (qacc[jj][tt][2] + qkvbS[jbase+2]) * 0.17677669529663687f;
                    float v3 = (qacc[jj][tt][3] + qkvbS[jbase+3]) * 0.17677669529663687f;
                    unsigned p0 = (unsigned short)f2bf(v0) | ((unsigned)(unsigned short)f2bf(v1) << 16);
                    unsigned p1 = (unsigned short)f2bf(v2) | ((unsigned)(unsigned short)f2bf(v3) << 16);
                    *(unsigned*)&qkvs[tok * 264 + jbase]     = p0;
                    *(unsigned*)&qkvs[tok * 264 + jbase + 2] = p1;
                } else if (jbase < 256) {
                    float v0 = qacc[jj][tt][0] + qkvbS[jbase+0];
                    float v1 = qacc[jj][tt][1] + qkvbS[jbase+1];
                    float v2 = qacc[jj][tt][2] + qkvbS[jbase+2];
                    float v3 = qacc[jj][tt][3] + qkvbS[jbase+3];
                    unsigned p0 = (unsigned short)f2bf(v0) | ((unsigned)(unsigned short)f2bf(v1) << 16);
                    unsigned p1 = (unsigned short)f2bf(v2) | ((unsigned)(unsigned short)f2bf(v3) << 16);
                    *(unsigned*)&qkvs[tok * 264 + jbase]     = p0;
                    *(unsigned*)&qkvs[tok * 264 + jbase + 2] = p1;
                } else {
                    #pragma unroll
                    for (int r = 0; r < 4; r++) {
                        int d = jbase - 256 + r;
                        Vt[(tt * 128 + d) * 24 + lm] = f2bf(qacc[jj][tt][r] + qkvbS[jbase + r]);
                    }
                }
            }
        }
    }
    __syncthreads();

    // ---- Stage 4: scores + bias + mask + softmax ------------------------
    {
        int w_ = wv >> 1;
        int hb = (wv & 1) * 2;
        int win = bid * 2 + w_;
        int wh = (win >> 6) & 63;
        int ww = win & 63;
        int m  = lm;
        int r2 = m >> 2, c2 = m & 3;
        int reg2 = regionOf(wh * 4 + r2) * 3 + regionOf(ww * 4 + c2);
        #pragma unroll
        for (int hh = 0; hh < 2; hh++) {
            int h = hb + hh;
            short8 qa = *(const short8*)&qkvs[(w_ * 16 + lm) * 264 + h * 32 + lq * 8];
            short8 kb = *(const short8*)&qkvs[(w_ * 16 + lm) * 264 + 128 + h * 32 + lq * 8];
            f32x4 s = __builtin_amdgcn_mfma_f32_16x16x32_bf16(qa, kb, (f32x4)0.0f, 0, 0, 0);
            #pragma unroll
            for (int r = 0; r < 4; r++) {
                int n = lq * 4 + r;
                int r1 = n >> 2, c1 = n & 3;
                int ridx = (r1 - r2 + 3) * 7 + (c1 - c2 + 3);
                float v = s[r] + rpbs[ridx * 4 + h];
                int reg1 = regionOf(wh * 4 + r1) * 3 + regionOf(ww * 4 + c1);
                if (reg1 != reg2) v -= 100.f;
                float mx = v;
                mx = fmaxf(mx, __shfl_xor(mx, 1));
                mx = fmaxf(mx, __shfl_xor(mx, 2));
                mx = fmaxf(mx, __shfl_xor(mx, 4));
                mx = fmaxf(mx, __shfl_xor(mx, 8));
                float e = __expf(v - mx);
                float ss = e;
                ss += __shfl_xor(ss, 1);
                ss += __shfl_xor(ss, 2);
                ss += __shfl_xor(ss, 4);
                ss += __shfl_xor(ss, 8);
                Ps[((w_ * 4 + h) * 16 + n) * 24 + m] = f2bf(e / ss);
            }
        }
    }
    __syncthreads();

    // ---- Stage 5: PV (zero-padded K=32 MFMA) ----------------------------
    {
        int w_ = wv >> 1;
        int hb = (wv & 1) * 2;
        #pragma unroll
        for (int hh = 0; hh < 2; hh++) {
            int h = hb + hh;
            #pragma unroll
            for (int dt = 0; dt < 2; dt++) {
                short8 pa = (short8)0;
                short8 vb = (short8)0;
                if (lq < 2) {
                    pa = *(const short8*)&Ps[((w_ * 4 + h) * 16 + lm) * 24 + lq * 8];
                    vb = *(const short8*)&Vt[(w_ * 128 + h * 32 + dt * 16 + lm) * 24 + lq * 8];
                }
                f32x4 o = __builtin_amdgcn_mfma_f32_16x16x32_bf16(pa, vb, (f32x4)0.0f, 0, 0, 0);
                #pragma unroll
                for (int r = 0; r < 4; r++) {
                    aoutS[(w_ * 16 + lq * 4 + r) * 136 + h * 32 + dt * 16 + lm] = f2bf(o[r]);
                }
            }
        }
    }
    __syncthreads();

    // ---- Stage 6: proj GEMM + shortcut ----------------------------------
    {
        f32x4 cacc[2][2];
        #pragma unroll
        for (int a = 0; a < 2; a++)
            #pragma unroll
            for (int t = 0; t < 2; t++) cacc[a][t] = (f32x4)0.0f;

        for (int ks = 0; ks < 4; ks++) {
            short8 af[2];
            #pragma unroll
            for (int jj = 0; jj < 2; jj++) {
                const int4v* gp = (const int4v*)(projw_rep +
                    (size_t)(wv * 32 + jj * 16 + lm) * 128 + ks * 32 + lq * 8);
                af[jj] = __builtin_bit_cast(short8, *gp);
            }
            short8 bfr[2];
            #pragma unroll
            for (int tt = 0; tt < 2; tt++)
                bfr[tt] = *(const short8*)&aoutS[(tt * 16 + lm) * 136 + ks * 32 + lq * 8];
            #pragma unroll
            for (int jj = 0; jj < 2; jj++)
                #pragma unroll
                for (int tt = 0; tt < 2; tt++)
                    cacc[jj][tt] = __builtin_amdgcn_mfma_f32_16x16x32_bf16(
                        af[jj], bfr[tt], cacc[jj][tt], 0, 0, 0);
        }
        __syncthreads();
        #pragma unroll
        for (int jj = 0; jj < 2; jj++) {
            int jbase = wv * 32 + jj * 16 + lq * 4;
            #pragma unroll
            for (int tt = 0; tt < 2; tt++) {
                int tok = tt * 16 + lm;
                float v0 = cacc[jj][tt][0] + projbS[jbase+0] + bf2f(Xb[tok * 136 + jbase+0]);
                float v1 = cacc[jj][tt][1] + projbS[jbase+1] + bf2f(Xb[tok * 136 + jbase+1]);
                float v2 = cacc[jj][tt][2] + projbS[jbase+2] + bf2f(Xb[tok * 136 + jbase+2]);
                float v3 = cacc[jj][tt][3] + projbS[jbase+3] + bf2f(Xb[tok * 136 + jbase+3]);
                unsigned p0 = (unsigned short)f2bf(v0) | ((unsigned)(unsigned short)f2bf(v1) << 16);
                unsigned p1 = (unsigned short)f2bf(v2) | ((unsigned)(unsigned short)f2bf(v3) << 16);
                *(unsigned*)&aoutS[tok * 136 + jbase]     = p0;
                *(unsigned*)&aoutS[tok * 136 + jbase + 2] = p1;
            }
        }
    }
    __syncthreads();

    // ---- Stage 7: NHWC store (rolled channel slot, 8B-aligned) ----------
    {
        #pragma unroll
        for (int k = 0; k < 4; k++) {
            int idx = k * 256 + tid;
            int j  = idx & 127;
            int c  = (idx >> 7) & 3;
            int w_ = idx >> 9;
            int win = bid * 2 + w_;
            int b   = win >> 12;
            int wh  = (win >> 6) & 63;
            int ww  = win & 63;
            int gw  = (ww * 4 + c + SHIFT) & 255;
            int slot0 = (wh * 4 + SHIFT + 1) & 255;   // multiple of 4, contiguous r=0..3
            unsigned short s0 = (unsigned short)aoutS[(w_ * 16 + 0 + c) * 136 + j];
            unsigned short s1 = (unsigned short)aoutS[(w_ * 16 + 4 + c) * 136 + j];
            unsigned short s2 = (unsigned short)aoutS[(w_ * 16 + 8 + c) * 136 + j];
            unsigned short s3 = (unsigned short)aoutS[(w_ * 16 + 12 + c) * 136 + j];
            unsigned long long pk =
                (unsigned long long)s0 | ((unsigned long long)s1 << 16) |
                ((unsigned long long)s2 << 32) | ((unsigned long long)s3 << 48);
            size_t base = (((size_t)b * 256 + gw) * 128 + j) * 256 + slot0;
            *(unsigned long long*)(xatt + base) = pk;
        }
    }
}

// ---------------------------------------------------------------------------
// Weight repack for convs: fold BN scale, fp32 -> bf16, per-tap layout.
// roll: channel-slot roll of the INPUT tensor this conv consumes.
// ---------------------------------------------------------------------------
__global__ __launch_bounds__(256) void repack3(
    const float* __restrict__ w, const float* __restrict__ bias,
    const float* __restrict__ g_, const float* __restrict__ b_,
    const float* __restrict__ m_, const float* __restrict__ v_,
    __hip_bfloat16* __restrict__ wrep, float* __restrict__ cconst, int roll)
{
    int idx = blockIdx.x * 256 + threadIdx.x;       // < 589824
    int co = idx / 2304;
    int rem = idx - co * 2304;
    int ci = rem / 9;
    int tap = rem - ci * 9;
    float s = g_[co] * rsqrtf(v_[co] + 1e-5f);
    int ci_s = (ci + roll) & 255;
    size_t o = ((((size_t)(co >> 7) * 8 + (ci_s >> 5)) * 9 + tap) * 128 + (co & 127)) * 32 + (ci_s & 31);
    wrep[o] = __float2bfloat16(w[idx] * s);
    if (rem == 0) cconst[co] = bias[co] * s + (b_[co] - m_[co] * s);
}

__global__ __launch_bounds__(256) void repack1(
    const float* __restrict__ w, const float* __restrict__ bias,
    const float* __restrict__ g_, const float* __restrict__ b_,
    const float* __restrict__ m_, const float* __restrict__ v_,
    __hip_bfloat16* __restrict__ wrep, float* __restrict__ cconst)
{
    int idx = blockIdx.x * 256 + threadIdx.x;       // < 65536
    int co = idx >> 8, ci = idx & 255;
    float s = g_[co] * rsqrtf(v_[co] + 1e-5f);
    int ci_s = (ci + 1) & 255;                      // xatt is rolled by +1
    wrep[(((size_t)(co >> 7) * 8 + (ci_s >> 5)) * 128 + (co & 127)) * 32 + (ci_s & 31)] =
        __float2bfloat16(w[idx] * s);
    if (ci == 0) cconst[co] += bias[co] * s + (b_[co] - m_[co] * s);
}

// ---------------------------------------------------------------------------
// MFMA implicit-GEMM 3x3 conv on NHWC input (+ optional fused 1x1 branch).
// Block: 128 co x 128 w, one output row h.  Staging = pure vectorized copy
// (dwordx4 -> ds_write_b128), register-double-buffered across cb iterations.
// LDS tile: xs[row][w_slot][ci32], stride 40 shorts (80B -> b128-aligned).
// ---------------------------------------------------------------------------
template<int HAS_IDC, int OUT_BF16>
__global__ __launch_bounds__(256) void conv_mfma(
    const __hip_bfloat16* __restrict__ xin,   // NHWC (n,256,128,256)
    const __hip_bfloat16* __restrict__ xidc,  // NHWC or null
    const __hip_bfloat16* __restrict__ wrep,
    const __hip_bfloat16* __restrict__ wrepi,
    const float* __restrict__ cconst,
    void* __restrict__ outp)
{
    constexpr int NROWS = HAS_IDC ? 4 : 3;
    constexpr int NPER  = NROWS * 2;            // 16B chunks per thread per cb
    constexpr int NTAPS = HAS_IDC ? 10 : 9;
    __shared__ __align__(16) short xs[NROWS * 130 * 40];

    const int tid = threadIdx.x;
    const int l  = tid & 63;
    const int wv = tid >> 6;
    const int wave_co = (wv & 1) * 64;
    const int wave_w  = (wv >> 1) * 64;
    const int g = blockIdx.x & 1;
    const int h = (blockIdx.x >> 1) & 255;
    const int n = blockIdx.x >> 9;
    const int lq = l >> 4;
    const int lm = l & 15;

    // zero w-halo slots (only conv rows 0..2 have halo reads)
    if (tid < 192) {
        int row = tid >> 6;
        int side = (tid >> 5) & 1;
        int ci = tid & 31;
        xs[(row * 130 + (side ? 129 : 0)) * 40 + ci] = 0;
    }

    f32x4 acc[4][4];
    #pragma unroll
    for (int a = 0; a < 4; a++)
        #pragma unroll
        for (int b = 0; b < 4; b++) acc[a][b] = (f32x4)0.0f;

    int4v pre[NPER];
    // prefetch cb=0
    #pragma unroll
    for (int t = 0; t < NPER; t++) {
        int idx = t * 256 + tid;
        int c8  = idx & 3;
        int w   = (idx >> 2) & 127;
        int row = idx >> 9;
        int4v v = {0, 0, 0, 0};
        if (row < 3) {
            int hh = h - 1 + row;
            if (0 <= hh && hh < 256)
                v = *(const int4v*)(xin + ((((size_t)n * 256 + hh) * 128 + w) << 8) + c8 * 8);
        } else {
            v = *(const int4v*)(xidc + ((((size_t)n * 256 + h) * 128 + w) << 8) + c8 * 8);
        }
        pre[t] = v;
    }

    #pragma unroll 1
    for (int cb = 0; cb < 8; cb++) {
        __syncthreads();
        #pragma unroll
        for (int t = 0; t < NPER; t++) {
            int idx = t * 256 + tid;
            int c8  = idx & 3;
            int w   = (idx >> 2) & 127;
            int row = idx >> 9;
            *(int4v*)&xs[(row * 130 + w + 1) * 40 + c8 * 8] = pre[t];
        }
        __syncthreads();
        if (cb < 7) {
            #pragma unroll
            for (int t = 0; t < NPER; t++) {
                int idx = t * 256 + tid;
                int c8  = idx & 3;
                int w   = (idx >> 2) & 127;
                int row = idx >> 9;
                int4v v = {0, 0, 0, 0};
                if (row < 3) {
                    int hh = h - 1 + row;
                    if (0 <= hh && hh < 256)
                        v = *(const int4v*)(xin + ((((size_t)n * 256 + hh) * 128 + w) << 8)
                                            + (cb + 1) * 32 + c8 * 8);
                } else {
                    v = *(const int4v*)(xidc + ((((size_t)n * 256 + h) * 128 + w) << 8)
                                        + (cb + 1) * 32 + c8 * 8);
                }
                pre[t] = v;
            }
        }

        #pragma unroll 1
        for (int tap = 0; tap < NTAPS; tap++) {
            const __hip_bfloat16* ap;
            const short* bs;
            if (tap < 9) {
                int kh = tap / 3;
                int kw = tap - kh * 3;
                ap = wrep + ((((size_t)(g * 8 + cb) * 9 + tap)) << 12);
                bs = xs + (kh * 130 + wave_w + kw) * 40;
            } else {
                ap = wrepi + (((size_t)(g * 8 + cb)) << 12);
                bs = xs + (3 * 130 + wave_w + 1) * 40;
            }
            short8 afr[4];
            #pragma unroll
            for (int cs = 0; cs < 4; cs++) {
                const int4v* p4 = (const int4v*)(ap + (size_t)(wave_co + cs * 16 + lm) * 32 + lq * 8);
                afr[cs] = __builtin_bit_cast(short8, *p4);
            }
            #pragma unroll
            for (int ws = 0; ws < 4; ws++) {
                short8 bfr = __builtin_bit_cast(short8,
                    *(const int4v*)&bs[(ws * 16 + lm) * 40 + lq * 8]);
                #pragma unroll
                for (int cs = 0; cs < 4; cs++) {
                    acc[cs][ws] = __builtin_amdgcn_mfma_f32_16x16x32_bf16(
                        afr[cs], bfr, acc[cs][ws], 0, 0, 0);
                }
            }
        }
    }

    // ---- epilogue ---------------------------------------------------------
    #pragma unroll
    for (int cs = 0; cs < 4; cs++) {
        int co0 = g * 128 + wave_co + cs * 16 + lq * 4;
        float c0 = cconst[co0 + 0], c1 = cconst[co0 + 1];
        float c2 = cconst[co0 + 2], c3 = cconst[co0 + 3];
        #pragma unroll
        for (int ws = 0; ws < 4; ws++) {
            int w = wave_w + ws * 16 + lm;
            float v0 = fmaxf(acc[cs][ws][0] + c0, 0.f);
            float v1 = fmaxf(acc[cs][ws][1] + c1, 0.f);
            float v2 = fmaxf(acc[cs][ws][2] + c2, 0.f);
            float v3 = fmaxf(acc[cs][ws][3] + c3, 0.f);
            if (OUT_BF16) {
                // NHWC bf16: 4 consecutive co per lane -> one 8B store
                unsigned long long pk =
                    (unsigned long long)(unsigned short)f2bf(v0) |
                    ((unsigned long long)(unsigned short)f2bf(v1) << 16) |
                    ((unsigned long long)(unsigned short)f2bf(v2) << 32) |
                    ((unsigned long long)(unsigned short)f2bf(v3) << 48);
                size_t base = ((((size_t)n * 256 + h) * 128 + w) << 8) + co0;
                *(unsigned long long*)((__hip_bfloat16*)outp + base) = pk;
            } else {
                // NCHW fp32 final output: coalesced dword stores
                float* op = (float*)outp;
                op[(((size_t)n * 256 + co0 + 0) * 256 + h) * 128 + w] = v0;
                op[(((size_t)n * 256 + co0 + 1) * 256 + h) * 128 + w] = v1;
                op[(((size_t)n * 256 + co0 + 2) * 256 + h) * 128 + w] = v2;
                op[(((size_t)n * 256 + co0 + 3) * 256 + h) * 128 + w] = v3;
            }
        }
    }
}

// ---------------------------------------------------------------------------
extern "C" void kernel_launch(void* const* d_in, const int* in_sizes, int n_in,
                              void* d_out, int out_size, void* d_ws, size_t ws_size,
                              hipStream_t stream) {
    const float* x       = (const float*)d_in[0];
    const float* qkv_w   = (const float*)d_in[1];
    const float* qkv_b   = (const float*)d_in[2];
    const float* proj_w  = (const float*)d_in[3];
    const float* proj_b  = (const float*)d_in[4];
    const float* rpb     = (const float*)d_in[5];
    const float* conv1_w = (const float*)d_in[6];
    const float* conv1_b = (const float*)d_in[7];
    const float* bn1_g   = (const float*)d_in[8];
    const float* bn1_b   = (const float*)d_in[9];
    const float* bn1_m   = (const float*)d_in[10];
    const float* bn1_v   = (const float*)d_in[11];
    const float* conv2_w = (const float*)d_in[12];
    const float* conv2_b = (const float*)d_in[13];
    const float* bn2_g   = (const float*)d_in[14];
    const float* bn2_b   = (const float*)d_in[15];
    const float* bn2_m   = (const float*)d_in[16];
    const float* bn2_v   = (const float*)d_in[17];
    const float* idc_w   = (const float*)d_in[18];
    const float* idc_b   = (const float*)d_in[19];
    const float* bni_g   = (const float*)d_in[20];
    const float* bni_b   = (const float*)d_in[21];
    const float* bni_m   = (const float*)d_in[22];
    const float* bni_v   = (const float*)d_in[23];

    const size_t TE = (size_t)BATCH * 256 * 256 * 128;    // 33,554,432
    char* ws = (char*)d_ws;
    __hip_bfloat16* xatt  = (__hip_bfloat16*)(ws);
    __hip_bfloat16* y1    = (__hip_bfloat16*)(ws + TE * 2);
    __hip_bfloat16* wrep1 = (__hip_bfloat16*)(ws + TE * 4);
    __hip_bfloat16* wrep2 = (__hip_bfloat16*)(ws + TE * 4 + 1179648);
    __hip_bfloat16* wrepi = (__hip_bfloat16*)(ws + TE * 4 + 2359296);
    float*          c1    = (float*)(ws + TE * 4 + 2490368);
    float*          c2    = (float*)(ws + TE * 4 + 2491392);
    __hip_bfloat16* qkvw_rep = (__hip_bfloat16*)(ws + TE * 4 + 2492416);
    __hip_bfloat16* projw_rep= (__hip_bfloat16*)(ws + TE * 4 + 2590720);

    repack3<<<2304, 256, 0, stream>>>(conv1_w, conv1_b, bn1_g, bn1_b, bn1_m, bn1_v, wrep1, c1, 1);
    repack3<<<2304, 256, 0, stream>>>(conv2_w, conv2_b, bn2_g, bn2_b, bn2_m, bn2_v, wrep2, c2, 0);
    repack1<<<256, 256, 0, stream>>>(idc_w, idc_b, bni_g, bni_b, bni_m, bni_v, wrepi, c2);
    repack_attnw<<<256, 256, 0, stream>>>(qkv_w, proj_w, qkvw_rep, projw_rep);

    attn_kernel<<<8192, 256, 0, stream>>>(x, qkvw_rep, projw_rep, qkv_b, proj_b, rpb, xatt);

    conv_mfma<0, 1><<<2048, 256, 0, stream>>>(xatt, nullptr, wrep1, nullptr, c1, (void*)y1);
    conv_mfma<1, 0><<<2048, 256, 0, stream>>>(y1, xatt, wrep2, wrepi, c2, d_out);
}